// Round 7
// baseline (436.665 us; speedup 1.0000x reference)
//
#include <hip/hip_runtime.h>
#include <stdint.h>
#include <math.h>

#define NN 2048
#define BB 8
#define BN (BB*NN)
#define KK 16
#define EE (BN*KK)
#define HID 128
#define PROJ_D 256
#define QPB 16   // queries (waves) per knn block

typedef unsigned long long u64;

__device__ __forceinline__ u64 wave_min_u64(u64 v) {
  #pragma unroll
  for (int off = 32; off > 0; off >>= 1) {
    u64 o = __shfl_xor(v, off);
    v = o < v ? o : v;
  }
  return v;
}

// ---------------- kNN + fused degree count ----------------
// Exact histogram selection (see r5/r6 comments). Emission also bumps cnt[dst].
__global__ __launch_bounds__(1024) void knn_kernel(const float* __restrict__ pos,
                                                   int* __restrict__ nbr,
                                                   int* __restrict__ cnt) {
  __shared__ float4 Ps[NN];            // 32 KB
  __shared__ unsigned Hist[QPB * 256]; // 16 KB, private 256 bins per wave
  const int b  = blockIdx.x >> 7;
  const int qb = blockIdx.x & 127;
  const int wave = threadIdx.x >> 6;
  const int lane = threadIdx.x & 63;
  const int i = qb * QPB + wave;
  const float* P = pos + (size_t)b * NN * 3;

  for (int t = threadIdx.x; t < NN; t += 1024)
    Ps[t] = make_float4(P[t*3], P[t*3+1], P[t*3+2], 0.f);
  __syncthreads();

  const float4 pi = Ps[i];
  const float xi = pi.x, yi = pi.y, zi = pi.z;
  unsigned* H = &Hist[wave * 256];

  float d[32];
  #pragma unroll
  for (int t = 0; t < 32; t++) {
    int j = t * 64 + lane;
    float4 pj = Ps[j];
    float ax = fabsf(xi - pj.x), ay = fabsf(yi - pj.y), az = fabsf(zi - pj.z);
    float dx = fminf(ax, 1.0f - ax);
    float dy = fminf(ay, 1.0f - ay);
    float dz = fminf(az, 1.0f - az);
    float s = __fadd_rn(__fadd_rn(__fadd_rn(__fmul_rn(dx,dx), __fmul_rn(dy,dy)),
                                  __fmul_rn(dz,dz)), 1e-12f);
    d[t] = __fsqrt_rn(s);
  }

  float scale = 1024.0f;
  int bstar = 0; unsigned C = 0;
  for (;;) {
    *(uint4*)&H[lane * 4] = make_uint4(0u, 0u, 0u, 0u);
    #pragma unroll
    for (int t = 0; t < 32; t++) {
      int bin = (int)(d[t] * scale);
      if (bin < 256) atomicAdd(&H[bin], 1u);
    }
    uint4 cv = *(const uint4*)&H[lane * 4];
    unsigned s4 = cv.x + cv.y + cv.z + cv.w;
    unsigned incl = s4;
    #pragma unroll
    for (int off = 1; off < 64; off <<= 1) {
      unsigned v = __shfl_up(incl, off);
      if (lane >= off) incl += v;
    }
    unsigned total = __shfl(incl, 63);
    if (total >= 17u) {
      unsigned base = incl - s4;
      bool has = (incl >= 17u) && (base < 17u);
      u64 hmask = __ballot(has);
      int srcl = __ffsll((unsigned long long)hmask) - 1;
      int bl = 0; unsigned Cl = 0;
      if (has) {
        if (base + cv.x >= 17u)                    { bl = lane*4 + 0; Cl = base; }
        else if (base + cv.x + cv.y >= 17u)        { bl = lane*4 + 1; Cl = base + cv.x; }
        else if (base + cv.x + cv.y + cv.z >= 17u) { bl = lane*4 + 2; Cl = base + cv.x + cv.y; }
        else                                       { bl = lane*4 + 3; Cl = base + cv.x + cv.y + cv.z; }
      }
      bstar = __shfl(bl, srcl);
      C     = __shfl(Cl, srcl);
      break;
    }
    scale *= 0.25f;
  }
  const int m = 17 - (int)C;

  u64 lst[6];
  #pragma unroll
  for (int t = 0; t < 6; t++) lst[t] = ~0ull;
  #pragma unroll
  for (int t = 0; t < 32; t++) {
    int bin = (int)(d[t] * scale);
    u64 key = ((u64)__float_as_uint(d[t]) << 11) | (unsigned)(t * 64 + lane);
    u64 cand = (bin == bstar) ? key : ~0ull;
    if (cand < lst[5]) {
      lst[5] = cand;
      #pragma unroll
      for (int u = 5; u > 0; u--) {
        u64 a = lst[u-1], c2 = lst[u];
        lst[u-1] = a < c2 ? a : c2;
        lst[u]   = a < c2 ? c2 : a;
      }
    }
  }

  u64 kstar = 0;
  #pragma unroll 1
  for (int r = 0; r < m; r++) {
    u64 h0 = lst[0];
    u64 gm = wave_min_u64(h0);
    kstar = gm;
    bool win = (h0 == gm);
    #pragma unroll
    for (int u = 0; u < 5; u++) lst[u] = win ? lst[u+1] : lst[u];
    lst[5] = win ? ~0ull : lst[5];
  }

  int* outp = nbr + ((size_t)b * NN + i) * KK;
  int total = 0;
  #pragma unroll
  for (int t = 0; t < 32; t++) {
    int j = t * 64 + lane;
    u64 key = ((u64)__float_as_uint(d[t]) << 11) | (unsigned)j;
    bool pred = (key <= kstar) && (j != i);
    u64 msk = __ballot(pred);
    if (pred) {
      int ofs = total + __popcll(msk & ((1ull << lane) - 1ull));
      outp[ofs] = b * NN + j;
      atomicAdd(&cnt[b * NN + j], 1);    // fused degree count
    }
    total += __popcll(msk);
  }
}

// ---------------- CSR build ----------------
__global__ __launch_bounds__(256) void scan_kernel(const int* __restrict__ cnt,
                                                   int* __restrict__ row_ptr) {
  __shared__ int ps[256];
  int t = threadIdx.x;
  const int4* cv = (const int4*)(cnt + t * 64);
  int4 c[16];
  int s = 0;
  #pragma unroll
  for (int i = 0; i < 16; i++) {
    c[i] = cv[i];
    s += c[i].x + c[i].y + c[i].z + c[i].w;
  }
  ps[t] = s;
  __syncthreads();
  for (int off = 1; off < 256; off <<= 1) {
    int v = 0;
    if (t >= off) v = ps[t - off];
    __syncthreads();
    ps[t] += v;
    __syncthreads();
  }
  int run = t ? ps[t - 1] : 0;
  int4* rp = (int4*)(row_ptr + t * 64);
  #pragma unroll
  for (int i = 0; i < 16; i++) {
    int4 o;
    o.x = run; run += c[i].x;
    o.y = run; run += c[i].y;
    o.z = run; run += c[i].z;
    o.w = run; run += c[i].w;
    rp[i] = o;
  }
  if (t == 255) row_ptr[BN] = run;
}

__global__ __launch_bounds__(256) void fill_kernel(const int* __restrict__ nbr,
                                                   const int* __restrict__ row_ptr,
                                                   int* __restrict__ fill,
                                                   int* __restrict__ col) {
  int e = blockIdx.x * 256 + threadIdx.x;
  int d = nbr[e];
  int srcn = e >> 4;
  int p = row_ptr[d] + atomicAdd(&fill[d], 1);
  col[p] = srcn;
}

// ============ fused node-GEMM machinery ============
// 64-row x 128-col tile, 256 threads, 8x4 outputs/thread.
// Ws holds a 64x128 HALF of W (32 KB), staged twice per GEMM unit (K-split)
// -> As 32K + Ws 32K = 64 KB -> 2 blocks/CU (round-6 lesson: 96 KB/1 block
// exposed all staging).  __launch_bounds__(256,4) caps VGPR at 128 so both
// blocks fit their 8 waves.

__device__ __forceinline__ void zero_acc(float acc[8][4]) {
  #pragma unroll
  for (int r = 0; r < 8; r++)
    #pragma unroll
    for (int j = 0; j < 4; j++) acc[r][j] = 0.f;
}

__device__ __forceinline__ void stage_A(float* As, const float* Ap, int m0, int tid) {
  const float4* Apv = (const float4*)(Ap + (size_t)m0 * 128);
  #pragma unroll
  for (int it = 0; it < 8; it++)
    ((float4*)As)[tid + it * 256] = Apv[tid + it * 256];
}

__device__ __forceinline__ void stage_W(float* Ws, const float* Wp, int ldW,
                                        int n0, int halfIdx, int tid) {
  int row = tid >> 5, c4 = tid & 31;
  #pragma unroll
  for (int it = 0; it < 8; it++)
    ((float4*)Ws)[tid + it * 256] =
        *(const float4*)&Wp[(size_t)(halfIdx * 64 + row + it * 8) * ldW + n0 + c4 * 4];
}

__device__ __forceinline__ void accum_half(float acc[8][4], const float* Ws,
                                           const float* As, int halfIdx,
                                           int tx, int ty) {
  #pragma unroll 4
  for (int k4 = 0; k4 < 16; k4++) {
    float4 w0 = ((const float4*)Ws)[(k4 * 4 + 0) * 32 + tx];
    float4 w1 = ((const float4*)Ws)[(k4 * 4 + 1) * 32 + tx];
    float4 w2 = ((const float4*)Ws)[(k4 * 4 + 2) * 32 + tx];
    float4 w3 = ((const float4*)Ws)[(k4 * 4 + 3) * 32 + tx];
    #pragma unroll
    for (int r = 0; r < 8; r++) {
      float4 a = ((const float4*)As)[(ty + r * 8) * 32 + halfIdx * 16 + k4];
      acc[r][0] += a.x*w0.x + a.y*w1.x + a.z*w2.x + a.w*w3.x;
      acc[r][1] += a.x*w0.y + a.y*w1.y + a.z*w2.y + a.w*w3.y;
      acc[r][2] += a.x*w0.z + a.y*w1.z + a.z*w2.z + a.w*w3.z;
      acc[r][3] += a.x*w0.w + a.y*w1.w + a.z*w2.w + a.w*w3.w;
    }
  }
}

// one 128-K GEMM unit: acc += A(LDS) @ W[:, n0:n0+128]
__device__ __forceinline__ void unit(float acc[8][4], const float* Wp, int ldW,
                                     int n0, float* Ws, const float* As,
                                     int tid, int tx, int ty) {
  #pragma unroll 1
  for (int h = 0; h < 2; h++) {
    __syncthreads();                 // prior Ws readers done / As writes visible
    stage_W(Ws, Wp, ldW, n0, h, tid);
    __syncthreads();
    accum_half(acc, Ws, As, h, tx, ty);
  }
}

// ---------------- K1: enc0 + enc1 + msg0 pair ----------------
__global__ __launch_bounds__(256, 4) void enc_msg_kernel(
    const float* __restrict__ xG, const float* __restrict__ ew0,
    const float* __restrict__ eb0, const float* __restrict__ ew1,
    const float* __restrict__ eb1, const float* __restrict__ Wmt,
    const float* __restrict__ Wmb, const float* __restrict__ mb,
    float* __restrict__ hOutG, float* __restrict__ bufA,
    float* __restrict__ bufB) {
  __shared__ float Ws[64 * 128];
  __shared__ float As[64 * 128];
  __shared__ float Xs[64 * 5];
  const int tid = threadIdx.x, tx = tid & 31, ty = tid >> 5;
  const int m0 = blockIdx.x * 64;
  float acc[8][4];

  if (tid < 80) ((float4*)Xs)[tid] = *((const float4*)(xG + (size_t)m0 * 5) + tid);
  if (tid < 160) ((float4*)Ws)[tid] = ((const float4*)ew0)[tid];
  __syncthreads();
  {
    float4 bv = *(const float4*)&eb0[tx * 4];
    #pragma unroll
    for (int r = 0; r < 8; r++) {
      int row = ty + r * 8;
      float4 a = bv;
      #pragma unroll
      for (int d = 0; d < 5; d++) {
        float xv = Xs[row * 5 + d];
        float4 w = ((const float4*)Ws)[d * 32 + tx];
        a.x += xv * w.x; a.y += xv * w.y; a.z += xv * w.z; a.w += xv * w.w;
      }
      a.x = fmaxf(a.x, 0.f); a.y = fmaxf(a.y, 0.f);
      a.z = fmaxf(a.z, 0.f); a.w = fmaxf(a.w, 0.f);
      ((float4*)As)[row * 32 + tx] = a;
    }
  }

  zero_acc(acc);
  unit(acc, ew1, HID, 0, Ws, As, tid, tx, ty);
  __syncthreads();
  {
    float4 bv = *(const float4*)&eb1[tx * 4];
    #pragma unroll
    for (int r = 0; r < 8; r++) {
      int row = ty + r * 8;
      float4 o;
      o.x = fmaxf(acc[r][0] + bv.x, 0.f);
      o.y = fmaxf(acc[r][1] + bv.y, 0.f);
      o.z = fmaxf(acc[r][2] + bv.z, 0.f);
      o.w = fmaxf(acc[r][3] + bv.w, 0.f);
      *(float4*)&hOutG[((size_t)m0 + row) * HID + tx * 4] = o;
      ((float4*)As)[row * 32 + tx] = o;
    }
  }

  zero_acc(acc);
  unit(acc, Wmt, HID, 0, Ws, As, tid, tx, ty);
  #pragma unroll
  for (int r = 0; r < 8; r++) {
    int row = ty + r * 8;
    *(float4*)&bufA[((size_t)m0 + row) * HID + tx * 4] =
        make_float4(acc[r][0], acc[r][1], acc[r][2], acc[r][3]);
  }

  zero_acc(acc);
  unit(acc, Wmb, HID, 0, Ws, As, tid, tx, ty);
  {
    float4 bv = *(const float4*)&mb[tx * 4];
    #pragma unroll
    for (int r = 0; r < 8; r++) {
      int row = ty + r * 8;
      *(float4*)&bufB[((size_t)m0 + row) * HID + tx * 4] =
          make_float4(acc[r][0] + bv.x, acc[r][1] + bv.y,
                      acc[r][2] + bv.z, acc[r][3] + bv.w);
    }
  }
}

// ---------------- K2: upd_i + msg_{i+1} pair ----------------
__global__ __launch_bounds__(256, 4) void upd_msg_kernel(
    const float* __restrict__ hG, const float* __restrict__ aggG,
    const float* __restrict__ Wut, const float* __restrict__ Wub,
    const float* __restrict__ ub, const float* __restrict__ Wmt,
    const float* __restrict__ Wmb, const float* __restrict__ mb,
    float* __restrict__ hOutG, float* __restrict__ bufA,
    float* __restrict__ bufB) {
  __shared__ float Ws[64 * 128];
  __shared__ float As[64 * 128];
  const int tid = threadIdx.x, tx = tid & 31, ty = tid >> 5;
  const int m0 = blockIdx.x * 64;
  float acc[8][4];

  stage_A(As, hG, m0, tid);
  zero_acc(acc);
  unit(acc, Wut, HID, 0, Ws, As, tid, tx, ty);
  __syncthreads();                       // As(h) readers done
  stage_A(As, aggG, m0, tid);
  unit(acc, Wub, HID, 0, Ws, As, tid, tx, ty);

  __syncthreads();                       // As(agg) readers done
  {
    float4 bv = *(const float4*)&ub[tx * 4];
    #pragma unroll
    for (int r = 0; r < 8; r++) {
      int row = ty + r * 8;
      float4 hres = *(const float4*)&hG[((size_t)m0 + row) * HID + tx * 4];
      float4 o;
      o.x = hres.x + fmaxf(acc[r][0] + bv.x, 0.f);
      o.y = hres.y + fmaxf(acc[r][1] + bv.y, 0.f);
      o.z = hres.z + fmaxf(acc[r][2] + bv.z, 0.f);
      o.w = hres.w + fmaxf(acc[r][3] + bv.w, 0.f);
      *(float4*)&hOutG[((size_t)m0 + row) * HID + tx * 4] = o;
      ((float4*)As)[row * 32 + tx] = o;
    }
  }

  zero_acc(acc);
  unit(acc, Wmt, HID, 0, Ws, As, tid, tx, ty);
  #pragma unroll
  for (int r = 0; r < 8; r++) {
    int row = ty + r * 8;
    *(float4*)&bufA[((size_t)m0 + row) * HID + tx * 4] =
        make_float4(acc[r][0], acc[r][1], acc[r][2], acc[r][3]);
  }

  zero_acc(acc);
  unit(acc, Wmb, HID, 0, Ws, As, tid, tx, ty);
  {
    float4 bv = *(const float4*)&mb[tx * 4];
    #pragma unroll
    for (int r = 0; r < 8; r++) {
      int row = ty + r * 8;
      *(float4*)&bufB[((size_t)m0 + row) * HID + tx * 4] =
          make_float4(acc[r][0] + bv.x, acc[r][1] + bv.y,
                      acc[r][2] + bv.z, acc[r][3] + bv.w);
    }
  }
}

// ---------------- K3: upd_2 + proj0 + proj1 ----------------
__global__ __launch_bounds__(256, 4) void upd_proj_kernel(
    const float* __restrict__ hG, const float* __restrict__ aggG,
    const float* __restrict__ Wut, const float* __restrict__ Wub,
    const float* __restrict__ ub, const float* __restrict__ pw0,
    const float* __restrict__ pb0, const float* __restrict__ pw1,
    const float* __restrict__ pb1, float* __restrict__ hOutG,
    float* __restrict__ zOut) {
  __shared__ float Ws[64 * 128];
  __shared__ float As[64 * 128];
  const int tid = threadIdx.x, tx = tid & 31, ty = tid >> 5;
  const int m0 = blockIdx.x * 64;
  float acc[8][4];

  stage_A(As, hG, m0, tid);
  zero_acc(acc);
  unit(acc, Wut, HID, 0, Ws, As, tid, tx, ty);
  __syncthreads();
  stage_A(As, aggG, m0, tid);
  unit(acc, Wub, HID, 0, Ws, As, tid, tx, ty);

  __syncthreads();
  {
    float4 bv = *(const float4*)&ub[tx * 4];
    #pragma unroll
    for (int r = 0; r < 8; r++) {
      int row = ty + r * 8;
      float4 hres = *(const float4*)&hG[((size_t)m0 + row) * HID + tx * 4];
      float4 o;
      o.x = hres.x + fmaxf(acc[r][0] + bv.x, 0.f);
      o.y = hres.y + fmaxf(acc[r][1] + bv.y, 0.f);
      o.z = hres.z + fmaxf(acc[r][2] + bv.z, 0.f);
      o.w = hres.w + fmaxf(acc[r][3] + bv.w, 0.f);
      *(float4*)&hOutG[((size_t)m0 + row) * HID + tx * 4] = o;
      ((float4*)As)[row * 32 + tx] = o;
    }
  }

  // proj0: t = relu(h_final @ pw0 + pb0) -> As
  zero_acc(acc);
  unit(acc, pw0, HID, 0, Ws, As, tid, tx, ty);
  __syncthreads();
  {
    float4 bv = *(const float4*)&pb0[tx * 4];
    #pragma unroll
    for (int r = 0; r < 8; r++) {
      int row = ty + r * 8;
      float4 o;
      o.x = fmaxf(acc[r][0] + bv.x, 0.f);
      o.y = fmaxf(acc[r][1] + bv.y, 0.f);
      o.z = fmaxf(acc[r][2] + bv.z, 0.f);
      o.w = fmaxf(acc[r][3] + bv.w, 0.f);
      ((float4*)As)[row * 32 + tx] = o;
    }
  }

  // proj1: z = t @ pw1 + pb1, two 128-col blocks
  #pragma unroll 1
  for (int cb = 0; cb < 2; cb++) {
    zero_acc(acc);
    unit(acc, pw1, PROJ_D, cb * 128, Ws, As, tid, tx, ty);
    float4 bv = *(const float4*)&pb1[cb * 128 + tx * 4];
    #pragma unroll
    for (int r = 0; r < 8; r++) {
      int row = ty + r * 8;
      *(float4*)&zOut[((size_t)m0 + row) * PROJ_D + cb * 128 + tx * 4] =
          make_float4(acc[r][0] + bv.x, acc[r][1] + bv.y,
                      acc[r][2] + bv.z, acc[r][3] + bv.w);
    }
  }
}

// ---------------- fused message + mean-aggregation (2 nodes/block) --------
__global__ __launch_bounds__(256) void agg_kernel(const float* __restrict__ Abuf,
                                                  const float* __restrict__ Bbuf,
                                                  const int* __restrict__ row_ptr,
                                                  const int* __restrict__ col,
                                                  float* __restrict__ agg) {
  int j = blockIdx.x * 2 + (threadIdx.x >> 7);
  int c = threadIdx.x & 127;
  float bj = Bbuf[(size_t)j * HID + c];
  int s = row_ptr[j], e = row_ptr[j + 1];
  float acc = 0.f;
  int p = s;
  for (; p + 4 <= e; p += 4) {
    int i0 = col[p], i1 = col[p+1], i2 = col[p+2], i3 = col[p+3];
    float v0 = Abuf[(size_t)i0 * HID + c];
    float v1 = Abuf[(size_t)i1 * HID + c];
    float v2 = Abuf[(size_t)i2 * HID + c];
    float v3 = Abuf[(size_t)i3 * HID + c];
    acc += fmaxf(v0 + bj, 0.f) + fmaxf(v1 + bj, 0.f)
         + fmaxf(v2 + bj, 0.f) + fmaxf(v3 + bj, 0.f);
  }
  for (; p < e; p++) {
    int i = col[p];
    acc += fmaxf(Abuf[(size_t)i * HID + c] + bj, 0.f);
  }
  float deg = (float)(e - s);
  float inv = 1.0f / fmaxf(deg, 1.0f);
  agg[(size_t)j * HID + c] = acc * inv;
}

extern "C" void kernel_launch(void* const* d_in, const int* in_sizes, int n_in,
                              void* d_out, int out_size, void* d_ws, size_t ws_size,
                              hipStream_t stream) {
  (void)in_sizes; (void)n_in; (void)out_size; (void)ws_size;
  const float* x       = (const float*)d_in[0];
  const float* pos     = (const float*)d_in[1];
  const float* enc_w0  = (const float*)d_in[3];
  const float* enc_b0  = (const float*)d_in[4];
  const float* enc_w1  = (const float*)d_in[5];
  const float* enc_b1  = (const float*)d_in[6];
  const float* msg_w   = (const float*)d_in[7];
  const float* msg_b   = (const float*)d_in[8];
  const float* upd_w   = (const float*)d_in[9];
  const float* upd_b   = (const float*)d_in[10];
  const float* proj_w0 = (const float*)d_in[11];
  const float* proj_b0 = (const float*)d_in[12];
  const float* proj_w1 = (const float*)d_in[13];
  const float* proj_b1 = (const float*)d_in[14];

  char* ws = (char*)d_ws;
  size_t off = 0;
  auto alloc = [&](size_t bytes) -> void* {
    void* p = ws + off;
    off += (bytes + 255) & ~(size_t)255;
    return p;
  };
  int*   nbr     = (int*)alloc((size_t)EE * 4);
  int*   cnt     = (int*)alloc((size_t)BN * 4);
  int*   fill    = (int*)alloc((size_t)BN * 4);
  int*   row_ptr = (int*)alloc((size_t)(BN + 1) * 4);
  int*   col     = (int*)alloc((size_t)EE * 4);
  float* h_a     = (float*)alloc((size_t)BN * HID * 4);
  float* h_b     = (float*)alloc((size_t)BN * HID * 4);
  float* bufA    = (float*)alloc((size_t)BN * HID * 4);
  float* bufB    = (float*)alloc((size_t)BN * HID * 4);
  float* bufAgg  = (float*)alloc((size_t)BN * HID * 4);
  float* out     = (float*)d_out;
  float* hOut    = out + (size_t)BN * PROJ_D;

  hipMemsetAsync(cnt, 0, (size_t)BN * 4 * 2, stream);   // cnt + fill

  knn_kernel<<<BN / QPB, 1024, 0, stream>>>(pos, nbr, cnt);
  scan_kernel<<<1, 256, 0, stream>>>(cnt, row_ptr);
  fill_kernel<<<EE / 256, 256, 0, stream>>>(nbr, row_ptr, fill, col);

  // K1: enc0+enc1+msg0
  enc_msg_kernel<<<BN / 64, 256, 0, stream>>>(
      x, enc_w0, enc_b0, enc_w1, enc_b1,
      msg_w, msg_w + 128 * HID, msg_b, h_a, bufA, bufB);
  agg_kernel<<<BN / 2, 256, 0, stream>>>(bufA, bufB, row_ptr, col, bufAgg);

  // K2 round 0: upd0 + msg1
  upd_msg_kernel<<<BN / 64, 256, 0, stream>>>(
      h_a, bufAgg, upd_w, upd_w + 128 * HID, upd_b,
      msg_w + (size_t)1 * 256 * HID, msg_w + (size_t)1 * 256 * HID + 128 * HID,
      msg_b + 1 * HID, h_b, bufA, bufB);
  agg_kernel<<<BN / 2, 256, 0, stream>>>(bufA, bufB, row_ptr, col, bufAgg);

  // K2 round 1: upd1 + msg2
  upd_msg_kernel<<<BN / 64, 256, 0, stream>>>(
      h_b, bufAgg, upd_w + (size_t)1 * 256 * HID,
      upd_w + (size_t)1 * 256 * HID + 128 * HID, upd_b + 1 * HID,
      msg_w + (size_t)2 * 256 * HID, msg_w + (size_t)2 * 256 * HID + 128 * HID,
      msg_b + 2 * HID, h_a, bufA, bufB);
  agg_kernel<<<BN / 2, 256, 0, stream>>>(bufA, bufB, row_ptr, col, bufAgg);

  // K3: upd2 + proj0 + proj1
  upd_proj_kernel<<<BN / 64, 256, 0, stream>>>(
      h_a, bufAgg, upd_w + (size_t)2 * 256 * HID,
      upd_w + (size_t)2 * 256 * HID + 128 * HID, upd_b + 2 * HID,
      proj_w0, proj_b0, proj_w1, proj_b1, hOut, out);
}

// Round 8
// 323.930 us; speedup vs baseline: 1.3480x; 1.3480x over previous
//
#include <hip/hip_runtime.h>
#include <stdint.h>
#include <math.h>

#define NN 2048
#define BB 8
#define BN (BB*NN)
#define KK 16
#define EE (BN*KK)
#define HID 128
#define PROJ_D 256
#define QPB 16   // queries (waves) per knn block

typedef unsigned long long u64;

__device__ __forceinline__ u64 wave_min_u64(u64 v) {
  #pragma unroll
  for (int off = 32; off > 0; off >>= 1) {
    u64 o = __shfl_xor(v, off);
    v = o < v ? o : v;
  }
  return v;
}

// ---------------- kNN + fused degree count ----------------
__global__ __launch_bounds__(1024) void knn_kernel(const float* __restrict__ pos,
                                                   int* __restrict__ nbr,
                                                   int* __restrict__ cnt) {
  __shared__ float4 Ps[NN];            // 32 KB
  __shared__ unsigned Hist[QPB * 256]; // 16 KB, private 256 bins per wave
  const int b  = blockIdx.x >> 7;
  const int qb = blockIdx.x & 127;
  const int wave = threadIdx.x >> 6;
  const int lane = threadIdx.x & 63;
  const int i = qb * QPB + wave;
  const float* P = pos + (size_t)b * NN * 3;

  for (int t = threadIdx.x; t < NN; t += 1024)
    Ps[t] = make_float4(P[t*3], P[t*3+1], P[t*3+2], 0.f);
  __syncthreads();

  const float4 pi = Ps[i];
  const float xi = pi.x, yi = pi.y, zi = pi.z;
  unsigned* H = &Hist[wave * 256];

  float d[32];
  #pragma unroll
  for (int t = 0; t < 32; t++) {
    int j = t * 64 + lane;
    float4 pj = Ps[j];
    float ax = fabsf(xi - pj.x), ay = fabsf(yi - pj.y), az = fabsf(zi - pj.z);
    float dx = fminf(ax, 1.0f - ax);
    float dy = fminf(ay, 1.0f - ay);
    float dz = fminf(az, 1.0f - az);
    float s = __fadd_rn(__fadd_rn(__fadd_rn(__fmul_rn(dx,dx), __fmul_rn(dy,dy)),
                                  __fmul_rn(dz,dz)), 1e-12f);
    d[t] = __fsqrt_rn(s);
  }

  float scale = 1024.0f;
  int bstar = 0; unsigned C = 0;
  for (;;) {
    *(uint4*)&H[lane * 4] = make_uint4(0u, 0u, 0u, 0u);
    #pragma unroll
    for (int t = 0; t < 32; t++) {
      int bin = (int)(d[t] * scale);
      if (bin < 256) atomicAdd(&H[bin], 1u);
    }
    uint4 cv = *(const uint4*)&H[lane * 4];
    unsigned s4 = cv.x + cv.y + cv.z + cv.w;
    unsigned incl = s4;
    #pragma unroll
    for (int off = 1; off < 64; off <<= 1) {
      unsigned v = __shfl_up(incl, off);
      if (lane >= off) incl += v;
    }
    unsigned total = __shfl(incl, 63);
    if (total >= 17u) {
      unsigned base = incl - s4;
      bool has = (incl >= 17u) && (base < 17u);
      u64 hmask = __ballot(has);
      int srcl = __ffsll((unsigned long long)hmask) - 1;
      int bl = 0; unsigned Cl = 0;
      if (has) {
        if (base + cv.x >= 17u)                    { bl = lane*4 + 0; Cl = base; }
        else if (base + cv.x + cv.y >= 17u)        { bl = lane*4 + 1; Cl = base + cv.x; }
        else if (base + cv.x + cv.y + cv.z >= 17u) { bl = lane*4 + 2; Cl = base + cv.x + cv.y; }
        else                                       { bl = lane*4 + 3; Cl = base + cv.x + cv.y + cv.z; }
      }
      bstar = __shfl(bl, srcl);
      C     = __shfl(Cl, srcl);
      break;
    }
    scale *= 0.25f;
  }
  const int m = 17 - (int)C;

  u64 lst[6];
  #pragma unroll
  for (int t = 0; t < 6; t++) lst[t] = ~0ull;
  #pragma unroll
  for (int t = 0; t < 32; t++) {
    int bin = (int)(d[t] * scale);
    u64 key = ((u64)__float_as_uint(d[t]) << 11) | (unsigned)(t * 64 + lane);
    u64 cand = (bin == bstar) ? key : ~0ull;
    if (cand < lst[5]) {
      lst[5] = cand;
      #pragma unroll
      for (int u = 5; u > 0; u--) {
        u64 a = lst[u-1], c2 = lst[u];
        lst[u-1] = a < c2 ? a : c2;
        lst[u]   = a < c2 ? c2 : a;
      }
    }
  }

  u64 kstar = 0;
  #pragma unroll 1
  for (int r = 0; r < m; r++) {
    u64 h0 = lst[0];
    u64 gm = wave_min_u64(h0);
    kstar = gm;
    bool win = (h0 == gm);
    #pragma unroll
    for (int u = 0; u < 5; u++) lst[u] = win ? lst[u+1] : lst[u];
    lst[5] = win ? ~0ull : lst[5];
  }

  int* outp = nbr + ((size_t)b * NN + i) * KK;
  int total = 0;
  #pragma unroll
  for (int t = 0; t < 32; t++) {
    int j = t * 64 + lane;
    u64 key = ((u64)__float_as_uint(d[t]) << 11) | (unsigned)j;
    bool pred = (key <= kstar) && (j != i);
    u64 msk = __ballot(pred);
    if (pred) {
      int ofs = total + __popcll(msk & ((1ull << lane) - 1ull));
      outp[ofs] = b * NN + j;
      atomicAdd(&cnt[b * NN + j], 1);
    }
    total += __popcll(msk);
  }
}

// ---------------- CSR build ----------------
__global__ __launch_bounds__(256) void scan_kernel(const int* __restrict__ cnt,
                                                   int* __restrict__ row_ptr) {
  __shared__ int ps[256];
  int t = threadIdx.x;
  const int4* cv = (const int4*)(cnt + t * 64);
  int4 c[16];
  int s = 0;
  #pragma unroll
  for (int i = 0; i < 16; i++) {
    c[i] = cv[i];
    s += c[i].x + c[i].y + c[i].z + c[i].w;
  }
  ps[t] = s;
  __syncthreads();
  for (int off = 1; off < 256; off <<= 1) {
    int v = 0;
    if (t >= off) v = ps[t - off];
    __syncthreads();
    ps[t] += v;
    __syncthreads();
  }
  int run = t ? ps[t - 1] : 0;
  int4* rp = (int4*)(row_ptr + t * 64);
  #pragma unroll
  for (int i = 0; i < 16; i++) {
    int4 o;
    o.x = run; run += c[i].x;
    o.y = run; run += c[i].y;
    o.z = run; run += c[i].z;
    o.w = run; run += c[i].w;
    rp[i] = o;
  }
  if (t == 255) row_ptr[BN] = run;
}

__global__ __launch_bounds__(256) void fill_kernel(const int* __restrict__ nbr,
                                                   const int* __restrict__ row_ptr,
                                                   int* __restrict__ fill,
                                                   int* __restrict__ col) {
  int e = blockIdx.x * 256 + threadIdx.x;
  int d = nbr[e];
  int srcn = e >> 4;
  int p = row_ptr[d] + atomicAdd(&fill[d], 1);
  col[p] = srcn;
}

// ---------------- encoder layer 0: (BN,5)@(5,128)+relu ----------------
__global__ __launch_bounds__(256) void enc0_kernel(const float* __restrict__ x,
                                                   const float* __restrict__ w0,
                                                   const float* __restrict__ b0,
                                                   float* __restrict__ h) {
  int t = blockIdx.x * 256 + threadIdx.x;
  int m = t >> 5;
  int c = (t & 31) * 4;
  float xv[5];
  #pragma unroll
  for (int d = 0; d < 5; d++) xv[d] = x[m * 5 + d];
  float4 acc = *(const float4*)&b0[c];
  #pragma unroll
  for (int d = 0; d < 5; d++) {
    float4 w = *(const float4*)&w0[d * HID + c];
    acc.x += xv[d] * w.x; acc.y += xv[d] * w.y;
    acc.z += xv[d] * w.z; acc.w += xv[d] * w.w;
  }
  acc.x = fmaxf(acc.x, 0.f); acc.y = fmaxf(acc.y, 0.f);
  acc.z = fmaxf(acc.z, 0.f); acc.w = fmaxf(acc.w, 0.f);
  *(float4*)&h[(size_t)m * HID + c] = acc;
}

// ---------------- K-split W-in-LDS GEMM, 32-row tiles -----------------------
// Round-7 lesson: 1 block/CU exposes every stage/barrier.  Here Ws holds a
// 64x128 HALF of W (32 KB), re-staged between halves; As 32x128 (16 KB);
// 48 KB/block -> 3 blocks/CU resident (12 waves, 37.5% occ).  Short stage
// segments hide under co-resident blocks' FMA streams.
__device__ __forceinline__ void zero_acc4(float acc[4][4]) {
  #pragma unroll
  for (int r = 0; r < 4; r++)
    #pragma unroll
    for (int j = 0; j < 4; j++) acc[r][j] = 0.f;
}

__device__ __forceinline__ void stage_A32(float* As, const float* Ap, int m0, int tid) {
  const float4* Apv = (const float4*)(Ap + (size_t)m0 * 128);
  #pragma unroll
  for (int it = 0; it < 4; it++)
    ((float4*)As)[tid + it * 256] = Apv[tid + it * 256];
}

__device__ __forceinline__ void stage_Whalf(float* Ws, const float* Wp, int ldW,
                                            int n0, int halfIdx, int tid) {
  int row = tid >> 5, c4 = tid & 31;
  #pragma unroll
  for (int it = 0; it < 8; it++)
    ((float4*)Ws)[tid + it * 256] =
        *(const float4*)&Wp[(size_t)(halfIdx * 64 + row + it * 8) * ldW + n0 + c4 * 4];
}

__device__ __forceinline__ void accum_half32(float acc[4][4], const float* Ws,
                                             const float* As, int halfIdx,
                                             int tx, int ty) {
  #pragma unroll 4
  for (int k4 = 0; k4 < 16; k4++) {
    float4 w0 = ((const float4*)Ws)[(k4 * 4 + 0) * 32 + tx];
    float4 w1 = ((const float4*)Ws)[(k4 * 4 + 1) * 32 + tx];
    float4 w2 = ((const float4*)Ws)[(k4 * 4 + 2) * 32 + tx];
    float4 w3 = ((const float4*)Ws)[(k4 * 4 + 3) * 32 + tx];
    #pragma unroll
    for (int r = 0; r < 4; r++) {
      float4 a = ((const float4*)As)[(ty + r * 8) * 32 + halfIdx * 16 + k4];
      acc[r][0] += a.x*w0.x + a.y*w1.x + a.z*w2.x + a.w*w3.x;
      acc[r][1] += a.x*w0.y + a.y*w1.y + a.z*w2.y + a.w*w3.y;
      acc[r][2] += a.x*w0.z + a.y*w1.z + a.z*w2.z + a.w*w3.z;
      acc[r][3] += a.x*w0.w + a.y*w1.w + a.z*w2.w + a.w*w3.w;
    }
  }
}

template<int TWOPH, int RELU, int HASRES>
__device__ __forceinline__ void gemm_body32(
    const float* __restrict__ A1, const float* __restrict__ W1,
    const float* __restrict__ A2, const float* __restrict__ W2,
    const float* __restrict__ bias, const float* __restrict__ Res,
    float* __restrict__ out, int ldW, int ldOut, int m0, int n0,
    float* Ws, float* As) {
  const int tid = threadIdx.x;
  const int tx = tid & 31, ty = tid >> 5;

  float acc[4][4];
  zero_acc4(acc);

  #pragma unroll 1
  for (int ph = 0; ph < (TWOPH ? 2 : 1); ph++) {
    const float* Ap = ph ? A2 : A1;
    const float* Wp = ph ? W2 : W1;
    if (ph) __syncthreads();            // prior readers of As/Ws done
    stage_A32(As, Ap, m0, tid);
    stage_Whalf(Ws, Wp, ldW, n0, 0, tid);
    __syncthreads();
    accum_half32(acc, Ws, As, 0, tx, ty);
    __syncthreads();                    // half-0 readers done
    stage_Whalf(Ws, Wp, ldW, n0, 1, tid);
    __syncthreads();
    accum_half32(acc, Ws, As, 1, tx, ty);
  }

  const int n = n0 + tx * 4;
  float4 bv = make_float4(0.f, 0.f, 0.f, 0.f);
  if (bias) bv = *(const float4*)&bias[n];
  #pragma unroll
  for (int r = 0; r < 4; r++) {
    int m = m0 + ty + r * 8;
    float4 o;
    o.x = acc[r][0] + bv.x; o.y = acc[r][1] + bv.y;
    o.z = acc[r][2] + bv.z; o.w = acc[r][3] + bv.w;
    if (RELU) {
      o.x = fmaxf(o.x, 0.f); o.y = fmaxf(o.y, 0.f);
      o.z = fmaxf(o.z, 0.f); o.w = fmaxf(o.w, 0.f);
    }
    if (HASRES) {
      float4 rr = *(const float4*)&Res[(size_t)m * ldOut + n];
      o.x += rr.x; o.y += rr.y; o.z += rr.z; o.w += rr.w;
    }
    *(float4*)&out[(size_t)m * ldOut + n] = o;
  }
}

template<int TWOPH, int RELU, int HASRES>
__global__ __launch_bounds__(256) void gemmW(
    const float* __restrict__ A1, const float* __restrict__ W1,
    const float* __restrict__ A2, const float* __restrict__ W2,
    const float* __restrict__ bias, const float* __restrict__ Res,
    float* __restrict__ out, int ldW, int ldOut) {
  __shared__ float Ws[64 * 128];
  __shared__ float As[32 * 128];
  gemm_body32<TWOPH, RELU, HASRES>(A1, W1, A2, W2, bias, Res, out, ldW, ldOut,
                                   blockIdx.x * 32, blockIdx.y * 128, Ws, As);
}

// msg pair: y=0 -> A@Wtop -> outA ; y=1 -> A@Wbot+bias -> outB
__global__ __launch_bounds__(256) void msg_pair(
    const float* __restrict__ A, const float* __restrict__ Wtop,
    const float* __restrict__ Wbot, const float* __restrict__ bias,
    float* __restrict__ outA, float* __restrict__ outB) {
  __shared__ float Ws[64 * 128];
  __shared__ float As[32 * 128];
  const int y = blockIdx.y;
  gemm_body32<0, 0, 0>(A, y ? Wbot : Wtop, nullptr, nullptr,
                       y ? bias : nullptr, nullptr, y ? outB : outA,
                       HID, HID, blockIdx.x * 32, 0, Ws, As);
}

// ---------------- fused message + mean-aggregation (2 nodes/block) --------
__global__ __launch_bounds__(256) void agg_kernel(const float* __restrict__ Abuf,
                                                  const float* __restrict__ Bbuf,
                                                  const int* __restrict__ row_ptr,
                                                  const int* __restrict__ col,
                                                  float* __restrict__ agg) {
  int j = blockIdx.x * 2 + (threadIdx.x >> 7);
  int c = threadIdx.x & 127;
  float bj = Bbuf[(size_t)j * HID + c];
  int s = row_ptr[j], e = row_ptr[j + 1];
  float acc = 0.f;
  int p = s;
  for (; p + 4 <= e; p += 4) {
    int i0 = col[p], i1 = col[p+1], i2 = col[p+2], i3 = col[p+3];
    float v0 = Abuf[(size_t)i0 * HID + c];
    float v1 = Abuf[(size_t)i1 * HID + c];
    float v2 = Abuf[(size_t)i2 * HID + c];
    float v3 = Abuf[(size_t)i3 * HID + c];
    acc += fmaxf(v0 + bj, 0.f) + fmaxf(v1 + bj, 0.f)
         + fmaxf(v2 + bj, 0.f) + fmaxf(v3 + bj, 0.f);
  }
  for (; p < e; p++) {
    int i = col[p];
    acc += fmaxf(Abuf[(size_t)i * HID + c] + bj, 0.f);
  }
  float deg = (float)(e - s);
  float inv = 1.0f / fmaxf(deg, 1.0f);
  agg[(size_t)j * HID + c] = acc * inv;
}

extern "C" void kernel_launch(void* const* d_in, const int* in_sizes, int n_in,
                              void* d_out, int out_size, void* d_ws, size_t ws_size,
                              hipStream_t stream) {
  (void)in_sizes; (void)n_in; (void)out_size; (void)ws_size;
  const float* x       = (const float*)d_in[0];
  const float* pos     = (const float*)d_in[1];
  const float* enc_w0  = (const float*)d_in[3];
  const float* enc_b0  = (const float*)d_in[4];
  const float* enc_w1  = (const float*)d_in[5];
  const float* enc_b1  = (const float*)d_in[6];
  const float* msg_w   = (const float*)d_in[7];
  const float* msg_b   = (const float*)d_in[8];
  const float* upd_w   = (const float*)d_in[9];
  const float* upd_b   = (const float*)d_in[10];
  const float* proj_w0 = (const float*)d_in[11];
  const float* proj_b0 = (const float*)d_in[12];
  const float* proj_w1 = (const float*)d_in[13];
  const float* proj_b1 = (const float*)d_in[14];

  char* ws = (char*)d_ws;
  size_t off = 0;
  auto alloc = [&](size_t bytes) -> void* {
    void* p = ws + off;
    off += (bytes + 255) & ~(size_t)255;
    return p;
  };
  int*   nbr     = (int*)alloc((size_t)EE * 4);
  int*   cnt     = (int*)alloc((size_t)BN * 4);
  int*   fill    = (int*)alloc((size_t)BN * 4);
  int*   row_ptr = (int*)alloc((size_t)(BN + 1) * 4);
  int*   col     = (int*)alloc((size_t)EE * 4);
  float* h_a     = (float*)alloc((size_t)BN * HID * 4);
  float* h_b     = (float*)alloc((size_t)BN * HID * 4);
  float* bufA    = (float*)alloc((size_t)BN * HID * 4);
  float* bufB    = (float*)alloc((size_t)BN * HID * 4);
  float* bufAgg  = (float*)alloc((size_t)BN * HID * 4);
  float* out     = (float*)d_out;
  float* hOut    = out + (size_t)BN * PROJ_D;

  hipMemsetAsync(cnt, 0, (size_t)BN * 4 * 2, stream);   // cnt + fill

  knn_kernel<<<BN / QPB, 1024, 0, stream>>>(pos, nbr, cnt);
  scan_kernel<<<1, 256, 0, stream>>>(cnt, row_ptr);
  fill_kernel<<<EE / 256, 256, 0, stream>>>(nbr, row_ptr, fill, col);

  enc0_kernel<<<BN * 32 / 256, 256, 0, stream>>>(x, enc_w0, enc_b0, bufA);
  gemmW<0,1,0><<<dim3(BN / 32, 1), 256, 0, stream>>>(
      bufA, enc_w1, nullptr, nullptr, enc_b1, nullptr, h_a, HID, HID);

  float* hc = h_a;
  float* hn = h_b;
  for (int i = 0; i < 3; i++) {
    const float* Wm = msg_w + (size_t)i * 256 * HID;
    msg_pair<<<dim3(BN / 32, 2), 256, 0, stream>>>(
        hc, Wm, Wm + 128 * HID, msg_b + (size_t)i * HID, bufA, bufB);
    agg_kernel<<<BN / 2, 256, 0, stream>>>(bufA, bufB, row_ptr, col, bufAgg);
    const float* Wu = upd_w + (size_t)i * 256 * HID;
    float* target = (i == 2) ? hOut : hn;
    gemmW<1,1,1><<<dim3(BN / 32, 1), 256, 0, stream>>>(
        hc, Wu, bufAgg, Wu + 128 * HID, upd_b + (size_t)i * HID, hc, target, HID, HID);
    hn = hc; hc = target;
  }

  gemmW<0,1,0><<<dim3(BN / 32, 1), 256, 0, stream>>>(
      hc, proj_w0, nullptr, nullptr, proj_b0, nullptr, bufA, HID, HID);
  gemmW<0,0,0><<<dim3(BN / 32, 2), 256, 0, stream>>>(
      bufA, proj_w1, nullptr, nullptr, proj_b1, nullptr, out, PROJ_D, PROJ_D);
}

// Round 9
// 244.029 us; speedup vs baseline: 1.7894x; 1.3274x over previous
//
#include <hip/hip_runtime.h>
#include <stdint.h>
#include <math.h>

#define NN 2048
#define BB 8
#define BN (BB*NN)
#define KK 16
#define EE (BN*KK)
#define HID 128
#define PROJ_D 256
#define QPB 16   // queries (waves) per knn block

typedef unsigned long long u64;
typedef unsigned short ushort_t;
typedef __attribute__((ext_vector_type(8))) short short8;
typedef __attribute__((ext_vector_type(4))) float f32x4;

__device__ __forceinline__ u64 wave_min_u64(u64 v) {
  #pragma unroll
  for (int off = 32; off > 0; off >>= 1) {
    u64 o = __shfl_xor(v, off);
    v = o < v ? o : v;
  }
  return v;
}

// ---------------- kNN + fused degree count (round-5/6 design, unchanged) ----
__global__ __launch_bounds__(1024) void knn_kernel(const float* __restrict__ pos,
                                                   int* __restrict__ nbr,
                                                   int* __restrict__ cnt) {
  __shared__ float4 Ps[NN];
  __shared__ unsigned Hist[QPB * 256];
  const int b  = blockIdx.x >> 7;
  const int qb = blockIdx.x & 127;
  const int wave = threadIdx.x >> 6;
  const int lane = threadIdx.x & 63;
  const int i = qb * QPB + wave;
  const float* P = pos + (size_t)b * NN * 3;

  for (int t = threadIdx.x; t < NN; t += 1024)
    Ps[t] = make_float4(P[t*3], P[t*3+1], P[t*3+2], 0.f);
  __syncthreads();

  const float4 pi = Ps[i];
  const float xi = pi.x, yi = pi.y, zi = pi.z;
  unsigned* H = &Hist[wave * 256];

  float d[32];
  #pragma unroll
  for (int t = 0; t < 32; t++) {
    int j = t * 64 + lane;
    float4 pj = Ps[j];
    float ax = fabsf(xi - pj.x), ay = fabsf(yi - pj.y), az = fabsf(zi - pj.z);
    float dx = fminf(ax, 1.0f - ax);
    float dy = fminf(ay, 1.0f - ay);
    float dz = fminf(az, 1.0f - az);
    float s = __fadd_rn(__fadd_rn(__fadd_rn(__fmul_rn(dx,dx), __fmul_rn(dy,dy)),
                                  __fmul_rn(dz,dz)), 1e-12f);
    d[t] = __fsqrt_rn(s);
  }

  float scale = 1024.0f;
  int bstar = 0; unsigned C = 0;
  for (;;) {
    *(uint4*)&H[lane * 4] = make_uint4(0u, 0u, 0u, 0u);
    #pragma unroll
    for (int t = 0; t < 32; t++) {
      int bin = (int)(d[t] * scale);
      if (bin < 256) atomicAdd(&H[bin], 1u);
    }
    uint4 cv = *(const uint4*)&H[lane * 4];
    unsigned s4 = cv.x + cv.y + cv.z + cv.w;
    unsigned incl = s4;
    #pragma unroll
    for (int off = 1; off < 64; off <<= 1) {
      unsigned v = __shfl_up(incl, off);
      if (lane >= off) incl += v;
    }
    unsigned total = __shfl(incl, 63);
    if (total >= 17u) {
      unsigned base = incl - s4;
      bool has = (incl >= 17u) && (base < 17u);
      u64 hmask = __ballot(has);
      int srcl = __ffsll((unsigned long long)hmask) - 1;
      int bl = 0; unsigned Cl = 0;
      if (has) {
        if (base + cv.x >= 17u)                    { bl = lane*4 + 0; Cl = base; }
        else if (base + cv.x + cv.y >= 17u)        { bl = lane*4 + 1; Cl = base + cv.x; }
        else if (base + cv.x + cv.y + cv.z >= 17u) { bl = lane*4 + 2; Cl = base + cv.x + cv.y; }
        else                                       { bl = lane*4 + 3; Cl = base + cv.x + cv.y + cv.z; }
      }
      bstar = __shfl(bl, srcl);
      C     = __shfl(Cl, srcl);
      break;
    }
    scale *= 0.25f;
  }
  const int m = 17 - (int)C;

  u64 lst[6];
  #pragma unroll
  for (int t = 0; t < 6; t++) lst[t] = ~0ull;
  #pragma unroll
  for (int t = 0; t < 32; t++) {
    int bin = (int)(d[t] * scale);
    u64 key = ((u64)__float_as_uint(d[t]) << 11) | (unsigned)(t * 64 + lane);
    u64 cand = (bin == bstar) ? key : ~0ull;
    if (cand < lst[5]) {
      lst[5] = cand;
      #pragma unroll
      for (int u = 5; u > 0; u--) {
        u64 a = lst[u-1], c2 = lst[u];
        lst[u-1] = a < c2 ? a : c2;
        lst[u]   = a < c2 ? c2 : a;
      }
    }
  }

  u64 kstar = 0;
  #pragma unroll 1
  for (int r = 0; r < m; r++) {
    u64 h0 = lst[0];
    u64 gm = wave_min_u64(h0);
    kstar = gm;
    bool win = (h0 == gm);
    #pragma unroll
    for (int u = 0; u < 5; u++) lst[u] = win ? lst[u+1] : lst[u];
    lst[5] = win ? ~0ull : lst[5];
  }

  int* outp = nbr + ((size_t)b * NN + i) * KK;
  int total = 0;
  #pragma unroll
  for (int t = 0; t < 32; t++) {
    int j = t * 64 + lane;
    u64 key = ((u64)__float_as_uint(d[t]) << 11) | (unsigned)j;
    bool pred = (key <= kstar) && (j != i);
    u64 msk = __ballot(pred);
    if (pred) {
      int ofs = total + __popcll(msk & ((1ull << lane) - 1ull));
      outp[ofs] = b * NN + j;
      atomicAdd(&cnt[b * NN + j], 1);
    }
    total += __popcll(msk);
  }
}

// ---------------- CSR build ----------------
__global__ __launch_bounds__(256) void scan_kernel(const int* __restrict__ cnt,
                                                   int* __restrict__ row_ptr) {
  __shared__ int ps[256];
  int t = threadIdx.x;
  const int4* cv = (const int4*)(cnt + t * 64);
  int4 c[16];
  int s = 0;
  #pragma unroll
  for (int i = 0; i < 16; i++) {
    c[i] = cv[i];
    s += c[i].x + c[i].y + c[i].z + c[i].w;
  }
  ps[t] = s;
  __syncthreads();
  for (int off = 1; off < 256; off <<= 1) {
    int v = 0;
    if (t >= off) v = ps[t - off];
    __syncthreads();
    ps[t] += v;
    __syncthreads();
  }
  int run = t ? ps[t - 1] : 0;
  int4* rp = (int4*)(row_ptr + t * 64);
  #pragma unroll
  for (int i = 0; i < 16; i++) {
    int4 o;
    o.x = run; run += c[i].x;
    o.y = run; run += c[i].y;
    o.z = run; run += c[i].z;
    o.w = run; run += c[i].w;
    rp[i] = o;
  }
  if (t == 255) row_ptr[BN] = run;
}

__global__ __launch_bounds__(256) void fill_kernel(const int* __restrict__ nbr,
                                                   const int* __restrict__ row_ptr,
                                                   int* __restrict__ fill,
                                                   int* __restrict__ col) {
  int e = blockIdx.x * 256 + threadIdx.x;
  int d = nbr[e];
  int srcn = e >> 4;
  int p = row_ptr[d] + atomicAdd(&fill[d], 1);
  col[p] = srcn;
}

// ---------------- encoder layer 0: (BN,5)@(5,128)+relu ----------------
__global__ __launch_bounds__(256) void enc0_kernel(const float* __restrict__ x,
                                                   const float* __restrict__ w0,
                                                   const float* __restrict__ b0,
                                                   float* __restrict__ h) {
  int t = blockIdx.x * 256 + threadIdx.x;
  int m = t >> 5;
  int c = (t & 31) * 4;
  float xv[5];
  #pragma unroll
  for (int d = 0; d < 5; d++) xv[d] = x[m * 5 + d];
  float4 acc = *(const float4*)&b0[c];
  #pragma unroll
  for (int d = 0; d < 5; d++) {
    float4 w = *(const float4*)&w0[d * HID + c];
    acc.x += xv[d] * w.x; acc.y += xv[d] * w.y;
    acc.z += xv[d] * w.z; acc.w += xv[d] * w.w;
  }
  acc.x = fmaxf(acc.x, 0.f); acc.y = fmaxf(acc.y, 0.f);
  acc.z = fmaxf(acc.z, 0.f); acc.w = fmaxf(acc.w, 0.f);
  *(float4*)&h[(size_t)m * HID + c] = acc;
}

// ================= split-bf16 MFMA GEMM machinery =================
// Round-8 diagnosis: fp32 GEMM invariant ~270us across occupancy configs ->
// LDS-throughput-bound (2 B/FLOP).  mfma_f32_16x16x32_bf16 needs ~0.4 B/FLOP
// even with the 3-term split (a_hi*b_hi + a_hi*b_lo + a_lo*b_hi), error ~1e-5.
// Layout: both A and B operands stored via the SAME (lane-group, elem)->k map
// (k = 32*kstep + 8*(lane>>4) + e), so any internal k-permutation cancels.
// D layout (HW-verified): col = lane&15, row = (lane>>4)*4 + reg.

__device__ __forceinline__ ushort_t bf16_rne(float x) {
  unsigned u = __float_as_uint(x);
  unsigned r = u + 0x7FFFu + ((u >> 16) & 1u);
  return (ushort_t)(r >> 16);
}
__device__ __forceinline__ float bf16_to_f(ushort_t h) {
  return __uint_as_float(((unsigned)h) << 16);
}

__device__ __forceinline__ void cvt8(const float4 f0, const float4 f1,
                                     short8& hi, short8& lo) {
  float f[8] = {f0.x, f0.y, f0.z, f0.w, f1.x, f1.y, f1.z, f1.w};
  #pragma unroll
  for (int e = 0; e < 8; e++) {
    ushort_t h = bf16_rne(f[e]);
    ushort_t l = bf16_rne(f[e] - bf16_to_f(h));
    hi[e] = (short)h;
    lo[e] = (short)l;
  }
}

// prep: convert 16 unit-Ws (each 128x128) to fragment-ordered bf16 hi/lo.
// unit u hi at wfrag + u*32768, lo at + 16384 (ushort counts).
// chunk c (0..2047): ks=c>>9, ct=(c>>6)&7, lane=c&63;
//   col = ct*16 + (lane&15); k0 = ks*32 + (lane>>4)*8.
__global__ __launch_bounds__(256) void prep_w_kernel(
    const float* __restrict__ enc_w1, const float* __restrict__ msg_w,
    const float* __restrict__ upd_w, const float* __restrict__ proj_w0,
    const float* __restrict__ proj_w1, ushort_t* __restrict__ wfrag) {
  int u = blockIdx.x >> 3;
  int c = (blockIdx.x & 7) * 256 + threadIdx.x;
  const float* src;
  int ldW = HID;
  if (u == 0) src = enc_w1;
  else if (u <= 6)  { int i = (u-1)>>1; int hf = (u-1)&1; src = msg_w + ((size_t)i*256 + hf*128) * HID; }
  else if (u <= 12) { int i = (u-7)>>1; int hf = (u-7)&1; src = upd_w + ((size_t)i*256 + hf*128) * HID; }
  else if (u == 13) src = proj_w0;
  else { src = proj_w1 + (u - 14) * 128; ldW = PROJ_D; }

  int ks = c >> 9, ct = (c >> 6) & 7, lane = c & 63;
  int colc = ct * 16 + (lane & 15);
  int k0 = ks * 32 + ((lane >> 4) << 3);
  float f[8];
  #pragma unroll
  for (int e = 0; e < 8; e++) f[e] = src[(size_t)(k0 + e) * ldW + colc];
  short8 hv, lv;
  cvt8(make_float4(f[0],f[1],f[2],f[3]), make_float4(f[4],f[5],f[6],f[7]), hv, lv);
  *(short8*)&wfrag[(size_t)u * 32768 + (size_t)c * 8] = hv;
  *(short8*)&wfrag[(size_t)u * 32768 + 16384 + (size_t)c * 8] = lv;
}

template<int PHASES, int RELU, int HASRES>
__device__ __forceinline__ void gemm_mfma_body(
    const float* __restrict__ A1, const ushort_t* __restrict__ wf1,
    const float* __restrict__ A2, const ushort_t* __restrict__ wf2,
    const float* __restrict__ bias, const float* __restrict__ Res,
    float* __restrict__ out, int ldOut, int n0,
    ushort_t* Ahi, ushort_t* Alo, ushort_t* Bhi, ushort_t* Blo) {
  const int tid = threadIdx.x, lane = tid & 63, wid = tid >> 6;
  const int m0 = blockIdx.x * 64;
  f32x4 zero = {0.f, 0.f, 0.f, 0.f};
  f32x4 acc[8];
  #pragma unroll
  for (int ct = 0; ct < 8; ct++) acc[ct] = zero;

  #pragma unroll 1
  for (int ph = 0; ph < PHASES; ph++) {
    const float* A = ph ? A2 : A1;
    const ushort_t* wf = ph ? wf2 : wf1;
    // stage A: 64 rows x 128 k, f32 -> bf16 hi/lo fragment chunks
    #pragma unroll
    for (int i = 0; i < 4; i++) {
      int c = tid + i * 256;
      int row = c >> 4, kg = c & 15;
      const float4* ap = (const float4*)(A + (((size_t)m0 + row) << 7) + (kg << 3));
      short8 hv, lv;
      cvt8(ap[0], ap[1], hv, lv);
      int idx = (((row >> 4) * 4 + (kg >> 2)) * 64 + ((row & 15) | ((kg & 3) << 4))) * 8;
      *(short8*)&Ahi[idx] = hv;
      *(short8*)&Alo[idx] = lv;
    }
    #pragma unroll 1
    for (int half = 0; half < 2; half++) {
      // stage B half (linear copy; wfrag already fragment-ordered)
      const short8* ghi = (const short8*)(wf + half * 8192);
      const short8* glo = (const short8*)(wf + 16384 + half * 8192);
      #pragma unroll
      for (int i = 0; i < 4; i++) {
        ((short8*)Bhi)[tid + i * 256] = ghi[tid + i * 256];
        ((short8*)Blo)[tid + i * 256] = glo[tid + i * 256];
      }
      __syncthreads();
      #pragma unroll
      for (int ks2 = 0; ks2 < 2; ks2++) {
        int ksA = half * 2 + ks2;
        short8 ah = *(const short8*)&Ahi[((wid * 4 + ksA) * 64 + lane) * 8];
        short8 al = *(const short8*)&Alo[((wid * 4 + ksA) * 64 + lane) * 8];
        #pragma unroll
        for (int ct = 0; ct < 8; ct++) {
          short8 bh = *(const short8*)&Bhi[((ks2 * 8 + ct) * 64 + lane) * 8];
          short8 bl = *(const short8*)&Blo[((ks2 * 8 + ct) * 64 + lane) * 8];
          acc[ct] = __builtin_amdgcn_mfma_f32_16x16x32_bf16(ah, bh, acc[ct], 0, 0, 0);
          acc[ct] = __builtin_amdgcn_mfma_f32_16x16x32_bf16(ah, bl, acc[ct], 0, 0, 0);
          acc[ct] = __builtin_amdgcn_mfma_f32_16x16x32_bf16(al, bh, acc[ct], 0, 0, 0);
        }
      }
      __syncthreads();
    }
  }

  const int rbase = m0 + wid * 16 + ((lane >> 4) << 2);
  const int cb = lane & 15;
  #pragma unroll
  for (int ct = 0; ct < 8; ct++) {
    int n = n0 + ct * 16 + cb;
    float bv = bias ? bias[n] : 0.f;
    #pragma unroll
    for (int r = 0; r < 4; r++) {
      float v = acc[ct][r] + bv;
      if (RELU) v = fmaxf(v, 0.f);
      if (HASRES) v += Res[(size_t)(rbase + r) * HID + n];
      out[(size_t)(rbase + r) * ldOut + n] = v;
    }
  }
}

template<int RELU>
__global__ __launch_bounds__(256, 4) void g1_kernel(
    const float* __restrict__ A, const ushort_t* __restrict__ wf,
    const float* __restrict__ bias, float* __restrict__ out) {
  __shared__ ushort_t Ahi[8192], Alo[8192], Bhi[8192], Blo[8192];
  gemm_mfma_body<1, RELU, 0>(A, wf, nullptr, nullptr, bias, nullptr,
                             out, HID, 0, Ahi, Alo, Bhi, Blo);
}

__global__ __launch_bounds__(256, 4) void msg_kernel(
    const float* __restrict__ h, const ushort_t* __restrict__ wfT,
    const ushort_t* __restrict__ wfB, const float* __restrict__ mb,
    float* __restrict__ bufA, float* __restrict__ bufB) {
  __shared__ ushort_t Ahi[8192], Alo[8192], Bhi[8192], Blo[8192];
  int y = blockIdx.y;
  gemm_mfma_body<1, 0, 0>(h, y ? wfB : wfT, nullptr, nullptr,
                          y ? mb : nullptr, nullptr, y ? bufB : bufA,
                          HID, 0, Ahi, Alo, Bhi, Blo);
}

__global__ __launch_bounds__(256, 4) void upd_kernel(
    const float* __restrict__ h, const ushort_t* __restrict__ wfT,
    const float* __restrict__ agg, const ushort_t* __restrict__ wfB,
    const float* __restrict__ ub, float* __restrict__ out) {
  __shared__ ushort_t Ahi[8192], Alo[8192], Bhi[8192], Blo[8192];
  gemm_mfma_body<2, 1, 1>(h, wfT, agg, wfB, ub, h,
                          out, HID, 0, Ahi, Alo, Bhi, Blo);
}

__global__ __launch_bounds__(256, 4) void proj1_kernel(
    const float* __restrict__ A, const ushort_t* __restrict__ wf01,
    const float* __restrict__ pb1, float* __restrict__ z) {
  __shared__ ushort_t Ahi[8192], Alo[8192], Bhi[8192], Blo[8192];
  int y = blockIdx.y;
  gemm_mfma_body<1, 0, 0>(A, wf01 + (size_t)y * 32768, nullptr, nullptr,
                          pb1, nullptr, z, PROJ_D, y * 128,
                          Ahi, Alo, Bhi, Blo);
}

// ---------------- fused message + mean-aggregation (2 nodes/block) --------
__global__ __launch_bounds__(256) void agg_kernel(const float* __restrict__ Abuf,
                                                  const float* __restrict__ Bbuf,
                                                  const int* __restrict__ row_ptr,
                                                  const int* __restrict__ col,
                                                  float* __restrict__ agg) {
  int j = blockIdx.x * 2 + (threadIdx.x >> 7);
  int c = threadIdx.x & 127;
  float bj = Bbuf[(size_t)j * HID + c];
  int s = row_ptr[j], e = row_ptr[j + 1];
  float acc = 0.f;
  int p = s;
  for (; p + 4 <= e; p += 4) {
    int i0 = col[p], i1 = col[p+1], i2 = col[p+2], i3 = col[p+3];
    float v0 = Abuf[(size_t)i0 * HID + c];
    float v1 = Abuf[(size_t)i1 * HID + c];
    float v2 = Abuf[(size_t)i2 * HID + c];
    float v3 = Abuf[(size_t)i3 * HID + c];
    acc += fmaxf(v0 + bj, 0.f) + fmaxf(v1 + bj, 0.f)
         + fmaxf(v2 + bj, 0.f) + fmaxf(v3 + bj, 0.f);
  }
  for (; p < e; p++) {
    int i = col[p];
    acc += fmaxf(Abuf[(size_t)i * HID + c] + bj, 0.f);
  }
  float deg = (float)(e - s);
  float inv = 1.0f / fmaxf(deg, 1.0f);
  agg[(size_t)j * HID + c] = acc * inv;
}

extern "C" void kernel_launch(void* const* d_in, const int* in_sizes, int n_in,
                              void* d_out, int out_size, void* d_ws, size_t ws_size,
                              hipStream_t stream) {
  (void)in_sizes; (void)n_in; (void)out_size; (void)ws_size;
  const float* x       = (const float*)d_in[0];
  const float* pos     = (const float*)d_in[1];
  const float* enc_w0  = (const float*)d_in[3];
  const float* enc_b0  = (const float*)d_in[4];
  const float* enc_w1  = (const float*)d_in[5];
  const float* enc_b1  = (const float*)d_in[6];
  const float* msg_w   = (const float*)d_in[7];
  const float* msg_b   = (const float*)d_in[8];
  const float* upd_w   = (const float*)d_in[9];
  const float* upd_b   = (const float*)d_in[10];
  const float* proj_w0 = (const float*)d_in[11];
  const float* proj_b0 = (const float*)d_in[12];
  const float* proj_w1 = (const float*)d_in[13];
  const float* proj_b1 = (const float*)d_in[14];

  char* ws = (char*)d_ws;
  size_t off = 0;
  auto alloc = [&](size_t bytes) -> void* {
    void* p = ws + off;
    off += (bytes + 255) & ~(size_t)255;
    return p;
  };
  int*      nbr     = (int*)alloc((size_t)EE * 4);
  int*      cnt     = (int*)alloc((size_t)BN * 4);
  int*      fill    = (int*)alloc((size_t)BN * 4);
  int*      row_ptr = (int*)alloc((size_t)(BN + 1) * 4);
  int*      col     = (int*)alloc((size_t)EE * 4);
  float*    h_a     = (float*)alloc((size_t)BN * HID * 4);
  float*    h_b     = (float*)alloc((size_t)BN * HID * 4);
  float*    bufA    = (float*)alloc((size_t)BN * HID * 4);
  float*    bufB    = (float*)alloc((size_t)BN * HID * 4);
  float*    bufAgg  = (float*)alloc((size_t)BN * HID * 4);
  ushort_t* wfrag   = (ushort_t*)alloc((size_t)16 * 32768 * 2);
  float*    out     = (float*)d_out;
  float*    hOut    = out + (size_t)BN * PROJ_D;

  hipMemsetAsync(cnt, 0, (size_t)BN * 4 * 2, stream);   // cnt + fill

  prep_w_kernel<<<128, 256, 0, stream>>>(enc_w1, msg_w, upd_w, proj_w0, proj_w1, wfrag);

  knn_kernel<<<BN / QPB, 1024, 0, stream>>>(pos, nbr, cnt);
  scan_kernel<<<1, 256, 0, stream>>>(cnt, row_ptr);
  fill_kernel<<<EE / 256, 256, 0, stream>>>(nbr, row_ptr, fill, col);

  enc0_kernel<<<BN * 32 / 256, 256, 0, stream>>>(x, enc_w0, enc_b0, bufA);
  g1_kernel<1><<<BN / 64, 256, 0, stream>>>(bufA, wfrag + 0 * 32768, enc_b1, h_a);

  float* hc = h_a;
  float* hn = h_b;
  for (int i = 0; i < 3; i++) {
    const ushort_t* wmT = wfrag + (size_t)(1 + 2 * i) * 32768;
    const ushort_t* wmB = wfrag + (size_t)(2 + 2 * i) * 32768;
    msg_kernel<<<dim3(BN / 64, 2), 256, 0, stream>>>(
        hc, wmT, wmB, msg_b + (size_t)i * HID, bufA, bufB);
    agg_kernel<<<BN / 2, 256, 0, stream>>>(bufA, bufB, row_ptr, col, bufAgg);
    const ushort_t* wuT = wfrag + (size_t)(7 + 2 * i) * 32768;
    const ushort_t* wuB = wfrag + (size_t)(8 + 2 * i) * 32768;
    float* target = (i == 2) ? hOut : hn;
    upd_kernel<<<BN / 64, 256, 0, stream>>>(
        hc, wuT, bufAgg, wuB, upd_b + (size_t)i * HID, target);
    hn = hc; hc = target;
  }

  g1_kernel<1><<<BN / 64, 256, 0, stream>>>(hc, wfrag + 13 * 32768, proj_b0, bufA);
  proj1_kernel<<<dim3(BN / 64, 2), 256, 0, stream>>>(
      bufA, wfrag + 14 * 32768, proj_b1, out);
}